// Round 5
// baseline (333.195 us; speedup 1.0000x reference)
//
#include <hip/hip_runtime.h>

#define A_ANCH 102400
#define BATCH  16
#define N_ANN  32
#define NLDM   196
#define ANNW   200     // 4 box + 196 landmark floats per annotation row
#define NB     64      // blocks per sample
#define APB    1600    // anchors per block = A_ANCH / NB
#define WING_CONST 0.25112780437753474f

// ws layout (bytes):
//  OFF_DONE   0      : int  done[B]                 (memset 64B each call)
//  OFF_PCNT   4KB    : int4 pcnt[B*NB]              plain stores
//  OFF_PSUM   64KB   : double psum[B*NB*3]          plain stores
//  OFF_BHIST  128KB  : uint bhist[B*NB*256]         plain stores (1 MB)
//  OFF_KEYS   2MB    : uint keys[B][A]              plain stores
//  OFF_CAND   16MB   : uint cand[B][A]              phase-2 local
#define OFF_DONE   0u
#define OFF_PCNT   4096u
#define OFF_PSUM   (64u << 10)
#define OFF_BHIST  (128u << 10)
#define OFF_KEYS   (2u << 20)
#define OFF_CAND   (16u << 20)

__device__ __forceinline__ float key_to_val(unsigned kk) {
    unsigned vb = (kk & 0x80000000u) ? (kk ^ 0x80000000u) : ~kk;
    return __uint_as_float(vb);
}

__global__ __launch_bounds__(256, 4) void k_fused(
    const float* __restrict__ cls,      // B*A*2
    const float* __restrict__ breg,     // B*A*4
    const float* __restrict__ lreg,     // B*A*196
    const float* __restrict__ anchors,  // A*4
    const float* __restrict__ ann,      // B*32*200
    int* __restrict__ done,
    int4* __restrict__ pcnt,
    double* __restrict__ psum,
    unsigned* __restrict__ bhist,
    unsigned* __restrict__ keys,
    unsigned* __restrict__ cand,
    float* __restrict__ out)
{
    const int tid = threadIdx.x;
    const int b   = blockIdx.x / NB;
    const int blk = blockIdx.x % NB;
    const int base = blk * APB;
    const int wave = tid >> 6, lane = tid & 63;

    __shared__ int    bh[256];
    __shared__ int    sci[4][3];
    __shared__ double scd[4][3];
    __shared__ int    s_flag;
    bh[tid] = 0;
    __syncthreads();

    const float* __restrict__ annb = ann + (size_t)b * N_ANN * ANNW;

    // ---------------- phase 1: per-anchor work over [base, base+APB) -------------
    int np = 0, nn = 0, nl = 0;
    double vp = 0.0, vb = 0.0, vl = 0.0;

    #pragma unroll 1
    for (int off = tid; off < APB; off += 256) {
        const int a = base + off;
        float4 av = *reinterpret_cast<const float4*>(anchors + (size_t)a * 4);
        const float aw = av.z - av.x, ah = av.w - av.y;
        const float areaA = aw * ah;

        // Division-free IoU argmax (boxes via wave-uniform scalar loads).
        // Shifted invalid boxes can't overlap anchors: inter==0 matches the
        // reference's -1 sentinel for both max and first-index argmax.
        float bnum = -1e30f, bden = 1.0f; int arg = 0;
        #pragma unroll 8
        for (int j = 0; j < N_ANN; ++j) {
            float4 bx = *reinterpret_cast<const float4*>(annb + (size_t)j * ANNW);
            float areaB = (bx.z - bx.x) * (bx.w - bx.y);
            float iw = fminf(av.z, bx.z) - fmaxf(av.x, bx.x);
            float ih = fminf(av.w, bx.w) - fmaxf(av.y, bx.y);
            iw = fmaxf(iw, 0.0f); ih = fmaxf(ih, 0.0f);
            float inter = iw * ih;
            float ua = fmaxf(areaA + areaB - inter, 1e-8f);
            bool upd = inter * bden > bnum * ua;
            bnum = upd ? inter : bnum;
            bden = upd ? ua : bden;
            arg  = upd ? j : arg;
        }
        const bool pos = bnum >= 0.7f * bden;
        const bool neg = bnum <  0.4f * bden;

        float2 c = *reinterpret_cast<const float2*>(cls + ((size_t)b * A_ANCH + a) * 2);

        float nv = -c.y;
        unsigned bits = __float_as_uint(nv);
        unsigned key = (bits & 0x80000000u) ? ~bits : (bits ^ 0x80000000u);
        keys[(size_t)b * A_ANCH + a] = neg ? key : 0u;
        if (neg) { atomicAdd(&bh[key >> 24], 1); nn++; }

        if (pos) {
            np++;
            vp += (double)(-c.x);

            const float acx = av.x + 0.5f * aw, acy = av.y + 0.5f * ah;
            float4 gb = *reinterpret_cast<const float4*>(annb + (size_t)arg * ANNW);
            float gw = gb.z - gb.x, gh = gb.w - gb.y;
            float gcx = gb.x + 0.5f * gw, gcy = gb.y + 0.5f * gh;
            float t0 = ((gcx - acx) / (aw + 1e-14f)) / 0.1f;
            float t1 = ((gcy - acy) / (ah + 1e-14f)) / 0.1f;
            float t2 = logf(gw / aw) / 0.2f;
            float t3 = logf(gh / ah) / 0.2f;

            float4 rv = *reinterpret_cast<const float4*>(breg + ((size_t)b * A_ANCH + a) * 4);
            float bsum = 0.0f, d;
            d = fabsf(t0 - rv.x); bsum += (d < 1.0f) ? 0.5f * d * d : d - 0.5f;
            d = fabsf(t1 - rv.y); bsum += (d < 1.0f) ? 0.5f * d * d : d - 0.5f;
            d = fabsf(t2 - rv.z); bsum += (d < 1.0f) ? 0.5f * d * d : d - 0.5f;
            d = fabsf(t3 - rv.w); bsum += (d < 1.0f) ? 0.5f * d * d : d - 0.5f;
            vb += (double)bsum;

            const float* gl = annb + (size_t)arg * ANNW + 4;  // 16B aligned
            float glsum = 0.0f;
            for (int i = 0; i < NLDM; i += 4) {
                float4 g4 = *reinterpret_cast<const float4*>(gl + i);
                glsum += g4.x + g4.y + g4.z + g4.w;
            }
            if (glsum > 0.0f) {
                nl++;
                const float* lr = lreg + ((size_t)b * A_ANCH + a) * NLDM; // 784B stride
                const float inv_aw = 1.0f / ((aw + 1e-14f) * 0.1f);
                const float inv_ah = 1.0f / ((ah + 1e-14f) * 0.1f);
                double wsum = 0.0;
                for (int i = 0; i < NLDM; i += 4) {
                    float4 l4 = *reinterpret_cast<const float4*>(lr + i);
                    float4 g4 = *reinterpret_cast<const float4*>(gl + i);
                    float s = (i < 68) ? 1.0f : 3.0f;   // 68 % 4 == 0: no straddle
                    float lt0 = (g4.x - acx) * inv_aw;
                    float lt1 = (g4.y - acy) * inv_ah;
                    float lt2 = (g4.z - acx) * inv_aw;
                    float lt3 = (g4.w - acy) * inv_ah;
                    float d0 = fabsf(lt0 * s - l4.x * s);
                    float d1 = fabsf(lt1 * s - l4.y * s);
                    float d2 = fabsf(lt2 * s - l4.z * s);
                    float d3 = fabsf(lt3 * s - l4.w * s);
                    float w0 = (d0 < 3.0f) ? 3.0f * log1pf(d0 * 0.5f) : d0 - WING_CONST;
                    float w1 = (d1 < 3.0f) ? 3.0f * log1pf(d1 * 0.5f) : d1 - WING_CONST;
                    float w2 = (d2 < 3.0f) ? 3.0f * log1pf(d2 * 0.5f) : d2 - WING_CONST;
                    float w3 = (d3 < 3.0f) ? 3.0f * log1pf(d3 * 0.5f) : d3 - WING_CONST;
                    wsum += (double)w0 + (double)w1 + (double)w2 + (double)w3;
                }
                vl += wsum;
            }
        }
    }

    // block reduction -> plain per-block stores
    #pragma unroll
    for (int o = 32; o > 0; o >>= 1) {
        np += __shfl_down(np, o); nn += __shfl_down(nn, o); nl += __shfl_down(nl, o);
        vp += __shfl_down(vp, o); vb += __shfl_down(vb, o); vl += __shfl_down(vl, o);
    }
    if (lane == 0) {
        sci[wave][0] = np; sci[wave][1] = nn; sci[wave][2] = nl;
        scd[wave][0] = vp; scd[wave][1] = vb; scd[wave][2] = vl;
    }
    __syncthreads();
    if (tid == 0) {
        int tnp = sci[0][0] + sci[1][0] + sci[2][0] + sci[3][0];
        int tnn = sci[0][1] + sci[1][1] + sci[2][1] + sci[3][1];
        int tnl = sci[0][2] + sci[1][2] + sci[2][2] + sci[3][2];
        pcnt[b * NB + blk] = make_int4(tnp, tnn, tnl, 0);
        size_t pb = (size_t)(b * NB + blk) * 3;
        psum[pb + 0] = scd[0][0] + scd[1][0] + scd[2][0] + scd[3][0];
        psum[pb + 1] = scd[0][1] + scd[1][1] + scd[2][1] + scd[3][1];
        psum[pb + 2] = scd[0][2] + scd[1][2] + scd[2][2] + scd[3][2];
    }
    bhist[(unsigned)((b * NB + blk) << 8) + (unsigned)tid] = (unsigned)bh[tid];

    // release: make this block's stores device-visible, then count in
    __threadfence();
    __syncthreads();
    if (tid == 0) {
        int old = atomicAdd(&done[b], 1);
        s_flag = (old == NB - 1) ? 1 : 0;
    }
    __syncthreads();
    if (!s_flag) return;
    __threadfence();   // acquire: invalidate caches before reading other blocks' data

    // ---------------- phase 2: selection (one block per sample) ----------------
    __shared__ unsigned shist[256];
    __shared__ int    s_i[8];   // npos,nneg,nl,keep,bin0,rem,hasgt,cnt
    __shared__ double s_d[5];   // acc0,acc1,acc2,negsum,total
    __shared__ unsigned s_prefix;
    __shared__ int s_r;
    __shared__ int s_cc;
    __shared__ double sredd[4];

    unsigned h = 0;
    #pragma unroll 8
    for (int k = 0; k < NB; ++k)
        h += bhist[(unsigned)((b * NB + k) << 8) + (unsigned)tid];
    shist[tid] = h;

    if (tid >= 64 && tid < 128) {   // hasgt in wave 1
        int j = tid - 64;
        bool v = (j < N_ANN) && (annb[(size_t)j * ANNW] > 0.0f);
        unsigned long long bm = __ballot(v);
        if (tid == 64) s_i[6] = (bm != 0ull) ? 1 : 0;
    }
    __syncthreads();

    if (tid < 64) {                 // fold counts/sums + derive bin0 in wave 0
        int4 p = pcnt[b * NB + tid];
        size_t pb = (size_t)(b * NB + tid) * 3;
        int xnp = p.x, xnn = p.y, xnl = p.z;
        double a0 = psum[pb], a1 = psum[pb + 1], a2 = psum[pb + 2];
        #pragma unroll
        for (int o = 32; o > 0; o >>= 1) {
            xnp += __shfl_down(xnp, o); xnn += __shfl_down(xnn, o); xnl += __shfl_down(xnl, o);
            a0 += __shfl_down(a0, o); a1 += __shfl_down(a1, o); a2 += __shfl_down(a2, o);
        }
        if (tid == 0) {
            int keep = min(xnn, 3 * xnp);
            int bin0 = -1, rem = 0;
            if (keep > 0) {
                unsigned cum = 0;
                for (int i = 255; i >= 0; --i) {
                    unsigned cc = shist[i];
                    if (cum + cc >= (unsigned)keep) { bin0 = i; rem = keep - (int)cum; break; }
                    cum += cc;
                }
            }
            s_i[0] = xnp; s_i[1] = xnn; s_i[2] = xnl;
            s_i[3] = keep; s_i[4] = bin0; s_i[5] = rem;
            s_d[0] = a0; s_d[1] = a1; s_d[2] = a2;
            s_d[4] = 0.0;
            s_cc = 0;
        }
    }
    __syncthreads();

    const int keep = s_i[3];
    const int bin0 = s_i[4];
    unsigned* cd = cand + (size_t)b * A_ANCH;

    if (keep > 0 && bin0 >= 0) {   // block-uniform branch: barriers inside are safe
        // scan keys: sum above bin0, compact bin0 matches to global cand
        double lneg = 0.0;
        const uint4* k4 = reinterpret_cast<const uint4*>(keys + (size_t)b * A_ANCH);
        const unsigned long long lmask = (1ull << lane) - 1ull;
        for (int i = tid; i < A_ANCH / 4; i += 256) {
            uint4 kv = k4[i];
            #pragma unroll
            for (int e = 0; e < 4; ++e) {
                unsigned kk = (e == 0) ? kv.x : (e == 1) ? kv.y : (e == 2) ? kv.z : kv.w;
                int top = (int)(kk >> 24);
                if (top > bin0) lneg += (double)key_to_val(kk);
                bool m = (top == bin0);
                unsigned long long bm = __ballot(m);
                if (bm) {
                    int ldr = __ffsll((long long)bm) - 1;
                    int bs = 0;
                    if (lane == ldr) bs = atomicAdd(&s_cc, (int)__popcll(bm));
                    bs = __shfl(bs, ldr);
                    if (m) cd[bs + (int)__popcll(bm & lmask)] = kk;
                }
            }
        }
        #pragma unroll
        for (int o = 32; o > 0; o >>= 1) lneg += __shfl_down(lneg, o);
        if (lane == 0) sredd[wave] = lneg;
        __syncthreads();
        if (tid == 0) {
            s_d[3] = sredd[0] + sredd[1] + sredd[2] + sredd[3];
            s_i[7] = s_cc;
        }
        __syncthreads();
        const int cnt = s_i[7];

        // radix passes 1..3 over candidates (L2-hot)
        unsigned prefix = ((unsigned)bin0) << 24;
        for (int pass = 1; pass < 4; ++pass) {
            const int shift = 24 - 8 * pass;
            const unsigned maskAbove = 0xFFFFFFFFu << (shift + 8);
            shist[tid] = 0;
            __syncthreads();
            for (int i = tid; i < cnt; i += 256) {
                unsigned kk = cd[i];
                if ((kk & maskAbove) == prefix)
                    atomicAdd(&shist[(kk >> shift) & 0xFFu], 1u);
            }
            __syncthreads();
            if (tid == 0) {
                int rem = (pass == 1) ? s_i[5] : s_r;
                unsigned cum = 0; unsigned npre = prefix; int nrem = rem;
                for (int bin = 255; bin >= 0; --bin) {
                    unsigned cc = shist[bin];
                    if (cum + cc >= (unsigned)rem) {
                        nrem = rem - (int)cum;
                        npre = prefix | ((unsigned)bin << shift);
                        break;
                    }
                    cum += cc;
                }
                s_r = nrem; s_prefix = npre;
            }
            __syncthreads();
            prefix = s_prefix;
        }
        const unsigned T = prefix;

        // tie-exact final sum
        double ls = 0.0;
        for (int i = tid; i < cnt; i += 256) {
            unsigned kk = cd[i];
            if (kk > T) ls += (double)key_to_val(kk);
        }
        #pragma unroll
        for (int o = 32; o > 0; o >>= 1) ls += __shfl_down(ls, o);
        __syncthreads();
        if (lane == 0) sredd[wave] = ls;
        __syncthreads();
        if (tid == 0)
            s_d[4] = s_d[3] + sredd[0] + sredd[1] + sredd[2] + sredd[3]
                   + (double)s_r * (double)key_to_val(T);
        __syncthreads();
    }

    if (tid == 0) {
        const int npos = s_i[0], nlc = s_i[2], hasgt = s_i[6];
        const double total = s_d[4];
        double cls_l = 0.0, bbox_l = 0.0, ldm_l = 0.0;
        if (hasgt && npos > 0) {
            double neg_mean = (keep > 0) ? total / (double)keep : 0.0;
            cls_l = s_d[0] / (double)npos + neg_mean;
            bbox_l = s_d[1] / ((double)npos * 4.0);
        }
        if (hasgt && nlc > 0) {
            ldm_l = s_d[2] / ((double)nlc * 196.0);
        }
        out[b]             = (float)cls_l;
        out[BATCH + b]     = (float)bbox_l;
        out[2 * BATCH + b] = (float)ldm_l;
    }
}

extern "C" void kernel_launch(void* const* d_in, const int* in_sizes, int n_in,
                              void* d_out, int out_size, void* d_ws, size_t ws_size,
                              hipStream_t stream) {
    const float* cls     = (const float*)d_in[0];
    const float* breg    = (const float*)d_in[1];
    const float* lreg    = (const float*)d_in[2];
    const float* anchors = (const float*)d_in[3];
    const float* ann     = (const float*)d_in[4];

    char* ws = (char*)d_ws;
    int*      done  = (int*)(ws + OFF_DONE);
    int4*     pcnt  = (int4*)(ws + OFF_PCNT);
    double*   psum  = (double*)(ws + OFF_PSUM);
    unsigned* bhist = (unsigned*)(ws + OFF_BHIST);
    unsigned* keys  = (unsigned*)(ws + OFF_KEYS);
    unsigned* cand  = (unsigned*)(ws + OFF_CAND);
    float*    out   = (float*)d_out;

    hipMemsetAsync(done, 0, BATCH * sizeof(int), stream);
    hipLaunchKernelGGL(k_fused, dim3(BATCH * NB), dim3(256), 0, stream,
                       cls, breg, lreg, anchors, ann,
                       done, pcnt, psum, bhist, keys, cand, out);
}

// Round 6
// 164.874 us; speedup vs baseline: 2.0209x; 2.0209x over previous
//
#include <hip/hip_runtime.h>

#define A_ANCH 102400
#define BATCH  16
#define N_ANN  32
#define NLDM   196
#define ANNW   200     // 4 box + 196 landmark floats per annotation row
#define NB     128     // blocks per sample
#define APB    800     // anchors per block = A_ANCH / NB
#define SEL_T  1024
#define CAP    14336   // LDS candidate cap; spill to global cand beyond
#define WING_CONST 0.25112780437753474f

// ws layout (bytes) — everything plain-stored, nothing needs zeroing:
//  OFF_PCNT   0      : int4   pcnt[B*NB]      (per-block npos,nneg,nl)  32 KB
//  OFF_PSUM   64KB   : double psum[B*NB*3]    (per-block sums)          48 KB
//  OFF_BHIST  128KB  : uint   bhist[B*NB*256] (per-block top-byte hist)  2 MB
//  OFF_KEYS   4MB    : uint   keys[B][A]                                6.5 MB
//  OFF_CAND   16MB   : uint   cand[B][A]      (k_sel-local scratch)
#define OFF_PCNT   0u
#define OFF_PSUM   (64u << 10)
#define OFF_BHIST  (128u << 10)
#define OFF_KEYS   (4u << 20)
#define OFF_CAND   (16u << 20)

__device__ __forceinline__ float key_to_val(unsigned kk) {
    unsigned vb = (kk & 0x80000000u) ? (kk ^ 0x80000000u) : ~kk;
    return __uint_as_float(vb);
}

__global__ __launch_bounds__(256) void k_main(
    const float* __restrict__ cls,      // B*A*2
    const float* __restrict__ breg,     // B*A*4
    const float* __restrict__ lreg,     // B*A*196
    const float* __restrict__ anchors,  // A*4
    const float* __restrict__ ann,      // B*32*200
    int4* __restrict__ pcnt,
    double* __restrict__ psum,
    unsigned* __restrict__ bhist,
    unsigned* __restrict__ keys)
{
    const int tid = threadIdx.x;
    const int b   = blockIdx.x / NB;
    const int blk = blockIdx.x % NB;
    const int base = blk * APB;
    const int wave = tid >> 6, lane = tid & 63;

    __shared__ int    bh[256];
    __shared__ int    sci[4][3];
    __shared__ double scd[4][3];
    bh[tid] = 0;
    __syncthreads();

    const float* __restrict__ annb = ann + (size_t)b * N_ANN * ANNW;

    int np = 0, nn = 0, nl = 0;
    double vp = 0.0, vb = 0.0, vl = 0.0;

    #pragma unroll 1
    for (int off = tid; off < APB; off += 256) {
        const int a = base + off;
        float4 av = *reinterpret_cast<const float4*>(anchors + (size_t)a * 4);
        const float aw = av.z - av.x, ah = av.w - av.y;
        const float areaA = aw * ah;

        // Division-free IoU argmax (boxes via wave-uniform loads).
        // Shifted invalid boxes can't overlap anchors: inter==0 matches the
        // reference's -1 sentinel for both max and first-index argmax.
        float bnum = -1e30f, bden = 1.0f; int arg = 0;
        #pragma unroll 8
        for (int j = 0; j < N_ANN; ++j) {
            float4 bx = *reinterpret_cast<const float4*>(annb + (size_t)j * ANNW);
            float areaB = (bx.z - bx.x) * (bx.w - bx.y);
            float iw = fminf(av.z, bx.z) - fmaxf(av.x, bx.x);
            float ih = fminf(av.w, bx.w) - fmaxf(av.y, bx.y);
            iw = fmaxf(iw, 0.0f); ih = fmaxf(ih, 0.0f);
            float inter = iw * ih;
            float ua = fmaxf(areaA + areaB - inter, 1e-8f);
            bool upd = inter * bden > bnum * ua;
            bnum = upd ? inter : bnum;
            bden = upd ? ua : bden;
            arg  = upd ? j : arg;
        }
        const bool pos = bnum >= 0.7f * bden;
        const bool neg = bnum <  0.4f * bden;

        float2 c = *reinterpret_cast<const float2*>(cls + ((size_t)b * A_ANCH + a) * 2);

        float nv = -c.y;
        unsigned bits = __float_as_uint(nv);
        unsigned key = (bits & 0x80000000u) ? ~bits : (bits ^ 0x80000000u);
        keys[(size_t)b * A_ANCH + a] = neg ? key : 0u;
        if (neg) { atomicAdd(&bh[key >> 24], 1); nn++; }

        if (pos) {
            np++;
            vp += (double)(-c.x);

            const float acx = av.x + 0.5f * aw, acy = av.y + 0.5f * ah;
            float4 gb = *reinterpret_cast<const float4*>(annb + (size_t)arg * ANNW);
            float gw = gb.z - gb.x, gh = gb.w - gb.y;
            float gcx = gb.x + 0.5f * gw, gcy = gb.y + 0.5f * gh;
            float t0 = ((gcx - acx) / (aw + 1e-14f)) / 0.1f;
            float t1 = ((gcy - acy) / (ah + 1e-14f)) / 0.1f;
            float t2 = logf(gw / aw) / 0.2f;
            float t3 = logf(gh / ah) / 0.2f;

            float4 rv = *reinterpret_cast<const float4*>(breg + ((size_t)b * A_ANCH + a) * 4);
            float bsum = 0.0f, d;
            d = fabsf(t0 - rv.x); bsum += (d < 1.0f) ? 0.5f * d * d : d - 0.5f;
            d = fabsf(t1 - rv.y); bsum += (d < 1.0f) ? 0.5f * d * d : d - 0.5f;
            d = fabsf(t2 - rv.z); bsum += (d < 1.0f) ? 0.5f * d * d : d - 0.5f;
            d = fabsf(t3 - rv.w); bsum += (d < 1.0f) ? 0.5f * d * d : d - 0.5f;
            vb += (double)bsum;

            const float* gl = annb + (size_t)arg * ANNW + 4;  // 16B aligned
            float glsum = 0.0f;
            for (int i = 0; i < NLDM; i += 4) {
                float4 g4 = *reinterpret_cast<const float4*>(gl + i);
                glsum += g4.x + g4.y + g4.z + g4.w;
            }
            if (glsum > 0.0f) {
                nl++;
                const float* lr = lreg + ((size_t)b * A_ANCH + a) * NLDM; // 784B stride
                const float inv_aw = 1.0f / ((aw + 1e-14f) * 0.1f);
                const float inv_ah = 1.0f / ((ah + 1e-14f) * 0.1f);
                double wsum = 0.0;
                for (int i = 0; i < NLDM; i += 4) {
                    float4 l4 = *reinterpret_cast<const float4*>(lr + i);
                    float4 g4 = *reinterpret_cast<const float4*>(gl + i);
                    float s = (i < 68) ? 1.0f : 3.0f;   // 68 % 4 == 0: no straddle
                    float lt0 = (g4.x - acx) * inv_aw;
                    float lt1 = (g4.y - acy) * inv_ah;
                    float lt2 = (g4.z - acx) * inv_aw;
                    float lt3 = (g4.w - acy) * inv_ah;
                    float d0 = fabsf(lt0 * s - l4.x * s);
                    float d1 = fabsf(lt1 * s - l4.y * s);
                    float d2 = fabsf(lt2 * s - l4.z * s);
                    float d3 = fabsf(lt3 * s - l4.w * s);
                    float w0 = (d0 < 3.0f) ? 3.0f * log1pf(d0 * 0.5f) : d0 - WING_CONST;
                    float w1 = (d1 < 3.0f) ? 3.0f * log1pf(d1 * 0.5f) : d1 - WING_CONST;
                    float w2 = (d2 < 3.0f) ? 3.0f * log1pf(d2 * 0.5f) : d2 - WING_CONST;
                    float w3 = (d3 < 3.0f) ? 3.0f * log1pf(d3 * 0.5f) : d3 - WING_CONST;
                    wsum += (double)w0 + (double)w1 + (double)w2 + (double)w3;
                }
                vl += wsum;
            }
        }
    }

    // block reduction -> plain per-block stores (no global atomics anywhere)
    #pragma unroll
    for (int o = 32; o > 0; o >>= 1) {
        np += __shfl_down(np, o); nn += __shfl_down(nn, o); nl += __shfl_down(nl, o);
        vp += __shfl_down(vp, o); vb += __shfl_down(vb, o); vl += __shfl_down(vl, o);
    }
    if (lane == 0) {
        sci[wave][0] = np; sci[wave][1] = nn; sci[wave][2] = nl;
        scd[wave][0] = vp; scd[wave][1] = vb; scd[wave][2] = vl;
    }
    __syncthreads();
    if (tid == 0) {
        pcnt[b * NB + blk] = make_int4(sci[0][0] + sci[1][0] + sci[2][0] + sci[3][0],
                                       sci[0][1] + sci[1][1] + sci[2][1] + sci[3][1],
                                       sci[0][2] + sci[1][2] + sci[2][2] + sci[3][2], 0);
        size_t pb = (size_t)(b * NB + blk) * 3;
        psum[pb + 0] = scd[0][0] + scd[1][0] + scd[2][0] + scd[3][0];
        psum[pb + 1] = scd[0][1] + scd[1][1] + scd[2][1] + scd[3][1];
        psum[pb + 2] = scd[0][2] + scd[1][2] + scd[2][2] + scd[3][2];
    }
    bhist[((unsigned)(b * NB + blk) << 8) + (unsigned)tid] = (unsigned)bh[tid];
}

__global__ __launch_bounds__(SEL_T) void k_sel(
    const float* __restrict__ ann,
    const int4* __restrict__ pcnt,
    const double* __restrict__ psum,
    const unsigned* __restrict__ bhist,
    const unsigned* __restrict__ keys,
    unsigned* __restrict__ cand,
    float* __restrict__ out)
{
    const int b = blockIdx.x;
    const int tid = threadIdx.x;
    const int wave = tid >> 6, lane = tid & 63;

    __shared__ unsigned part[SEL_T];
    __shared__ unsigned shist[256];
    __shared__ unsigned s_cand[CAP];
    __shared__ int    sredi[16][3];
    __shared__ double sredd[16][3];
    __shared__ int    s_i[8];   // npos,nneg,nl,keep,bin0,rem,hasgt,cnt
    __shared__ double s_d[5];   // acc0,acc1,acc2,negsum,total
    __shared__ unsigned s_prefix;
    __shared__ int s_r;
    __shared__ int s_cc;

    // 1. fold per-block histograms: bin = tid&255, chunk = tid>>8 covers 32 blocks
    {
        const unsigned bin = tid & 255u;
        const int chunk = tid >> 8;
        unsigned h = 0;
        #pragma unroll 8
        for (int j = chunk * 32; j < chunk * 32 + 32; ++j)
            h += bhist[((unsigned)(b * NB + j) << 8) + bin];
        part[tid] = h;
    }

    // 2. fold per-block counts/sums (NB=128 entries, threads 0..127)
    int np = 0, nn = 0, nl = 0;
    double a0 = 0.0, a1 = 0.0, a2 = 0.0;
    if (tid < NB) {
        int4 p = pcnt[b * NB + tid];
        np = p.x; nn = p.y; nl = p.z;
        size_t pb = (size_t)(b * NB + tid) * 3;
        a0 = psum[pb]; a1 = psum[pb + 1]; a2 = psum[pb + 2];
    }
    #pragma unroll
    for (int o = 32; o > 0; o >>= 1) {
        np += __shfl_down(np, o); nn += __shfl_down(nn, o); nl += __shfl_down(nl, o);
        a0 += __shfl_down(a0, o); a1 += __shfl_down(a1, o); a2 += __shfl_down(a2, o);
    }
    if (lane == 0) {
        sredi[wave][0] = np; sredi[wave][1] = nn; sredi[wave][2] = nl;
        sredd[wave][0] = a0; sredd[wave][1] = a1; sredd[wave][2] = a2;
    }

    // 3. hasgt (wave 2)
    if (tid >= 128 && tid < 192) {
        int j = tid - 128;
        bool v = (j < N_ANN) && (ann[((size_t)b * N_ANN + j) * ANNW] > 0.0f);
        unsigned long long bm = __ballot(v);
        if (tid == 128) s_i[6] = (bm != 0ull) ? 1 : 0;
    }
    __syncthreads();

    if (tid < 256) shist[tid] = part[tid] + part[tid + 256] + part[tid + 512] + part[tid + 768];
    __syncthreads();

    // 4. totals + derive bin0/rem
    if (tid == 0) {
        int tnp = 0, tnn = 0, tnl = 0; double t0 = 0, t1 = 0, t2 = 0;
        for (int w = 0; w < 16; ++w) {
            tnp += sredi[w][0]; tnn += sredi[w][1]; tnl += sredi[w][2];
            t0 += sredd[w][0]; t1 += sredd[w][1]; t2 += sredd[w][2];
        }
        int keep = min(tnn, 3 * tnp);
        int bin0 = -1, rem = 0;
        if (keep > 0) {
            unsigned cum = 0;
            for (int i = 255; i >= 0; --i) {
                unsigned cc = shist[i];
                if (cum + cc >= (unsigned)keep) { bin0 = i; rem = keep - (int)cum; break; }
                cum += cc;
            }
        }
        s_i[0] = tnp; s_i[1] = tnn; s_i[2] = tnl;
        s_i[3] = keep; s_i[4] = bin0; s_i[5] = rem;
        s_d[0] = t0; s_d[1] = t1; s_d[2] = t2;
        s_d[4] = 0.0;
        s_cc = 0;
    }
    __syncthreads();

    const int keep = s_i[3];
    const int bin0 = s_i[4];
    unsigned* cd = cand + (size_t)b * A_ANCH;

    if (keep > 0 && bin0 >= 0) {   // block-uniform: barriers inside are safe
        // 5. scan keys: negsum above bin0, compact bin0 matches
        double lneg = 0.0;
        const uint4* k4 = reinterpret_cast<const uint4*>(keys + (size_t)b * A_ANCH);
        const unsigned long long lmask = (1ull << lane) - 1ull;
        for (int i = tid; i < A_ANCH / 4; i += SEL_T) {
            uint4 kv = k4[i];
            #pragma unroll
            for (int e = 0; e < 4; ++e) {
                unsigned kk = (e == 0) ? kv.x : (e == 1) ? kv.y : (e == 2) ? kv.z : kv.w;
                int top = (int)(kk >> 24);
                if (top > bin0) lneg += (double)key_to_val(kk);
                bool m = (top == bin0);
                unsigned long long bm = __ballot(m);
                if (bm) {
                    int ldr = __ffsll((long long)bm) - 1;
                    int bs = 0;
                    if (lane == ldr) bs = atomicAdd(&s_cc, (int)__popcll(bm));
                    bs = __shfl(bs, ldr);
                    if (m) {
                        int idx = bs + (int)__popcll(bm & lmask);
                        if (idx < CAP) s_cand[idx] = kk;
                        else cd[idx - CAP] = kk;
                    }
                }
            }
        }
        #pragma unroll
        for (int o = 32; o > 0; o >>= 1) lneg += __shfl_down(lneg, o);
        __syncthreads();
        if (lane == 0) sredd[wave][0] = lneg;
        __syncthreads();
        if (tid == 0) {
            double t = 0.0;
            for (int w = 0; w < 16; ++w) t += sredd[w][0];
            s_d[3] = t;
            s_i[7] = s_cc;
        }
        __syncthreads();
        const int cnt = s_i[7];

        // 6. radix passes 1..3 over candidates
        unsigned prefix = ((unsigned)bin0) << 24;
        for (int pass = 1; pass < 4; ++pass) {
            const int shift = 24 - 8 * pass;
            const unsigned maskAbove = 0xFFFFFFFFu << (shift + 8);
            if (tid < 256) shist[tid] = 0;
            __syncthreads();
            for (int i = tid; i < cnt; i += SEL_T) {
                unsigned kk = (i < CAP) ? s_cand[i] : cd[i - CAP];
                if ((kk & maskAbove) == prefix)
                    atomicAdd(&shist[(kk >> shift) & 0xFFu], 1u);
            }
            __syncthreads();
            if (tid == 0) {
                int rem = (pass == 1) ? s_i[5] : s_r;
                unsigned cum = 0; unsigned npre = prefix; int nrem = rem;
                for (int bin = 255; bin >= 0; --bin) {
                    unsigned cc = shist[bin];
                    if (cum + cc >= (unsigned)rem) {
                        nrem = rem - (int)cum;
                        npre = prefix | ((unsigned)bin << shift);
                        break;
                    }
                    cum += cc;
                }
                s_r = nrem; s_prefix = npre;
            }
            __syncthreads();
            prefix = s_prefix;
        }
        const unsigned T = prefix;

        // 7. tie-exact final sum
        double ls = 0.0;
        for (int i = tid; i < cnt; i += SEL_T) {
            unsigned kk = (i < CAP) ? s_cand[i] : cd[i - CAP];
            if (kk > T) ls += (double)key_to_val(kk);
        }
        #pragma unroll
        for (int o = 32; o > 0; o >>= 1) ls += __shfl_down(ls, o);
        __syncthreads();
        if (lane == 0) sredd[wave][0] = ls;
        __syncthreads();
        if (tid == 0) {
            double cs = 0.0;
            for (int w = 0; w < 16; ++w) cs += sredd[w][0];
            s_d[4] = s_d[3] + cs + (double)s_r * (double)key_to_val(T);
        }
        __syncthreads();
    }

    if (tid == 0) {
        const int npos = s_i[0], nlc = s_i[2], hasgt = s_i[6];
        const double total = s_d[4];
        double cls_l = 0.0, bbox_l = 0.0, ldm_l = 0.0;
        if (hasgt && npos > 0) {
            double neg_mean = (keep > 0) ? total / (double)keep : 0.0;
            cls_l = s_d[0] / (double)npos + neg_mean;
            bbox_l = s_d[1] / ((double)npos * 4.0);
        }
        if (hasgt && nlc > 0) {
            ldm_l = s_d[2] / ((double)nlc * 196.0);
        }
        out[b]             = (float)cls_l;
        out[BATCH + b]     = (float)bbox_l;
        out[2 * BATCH + b] = (float)ldm_l;
    }
}

extern "C" void kernel_launch(void* const* d_in, const int* in_sizes, int n_in,
                              void* d_out, int out_size, void* d_ws, size_t ws_size,
                              hipStream_t stream) {
    const float* cls     = (const float*)d_in[0];
    const float* breg    = (const float*)d_in[1];
    const float* lreg    = (const float*)d_in[2];
    const float* anchors = (const float*)d_in[3];
    const float* ann     = (const float*)d_in[4];

    char* ws = (char*)d_ws;
    int4*     pcnt  = (int4*)(ws + OFF_PCNT);
    double*   psum  = (double*)(ws + OFF_PSUM);
    unsigned* bhist = (unsigned*)(ws + OFF_BHIST);
    unsigned* keys  = (unsigned*)(ws + OFF_KEYS);
    unsigned* cand  = (unsigned*)(ws + OFF_CAND);
    float*    out   = (float*)d_out;

    hipLaunchKernelGGL(k_main, dim3(BATCH * NB), dim3(256), 0, stream,
                       cls, breg, lreg, anchors, ann, pcnt, psum, bhist, keys);
    hipLaunchKernelGGL(k_sel, dim3(BATCH), dim3(SEL_T), 0, stream,
                       ann, pcnt, psum, bhist, keys, cand, out);
}